// Round 5
// baseline (1342.614 us; speedup 1.0000x reference)
//
#include <hip/hip_runtime.h>
#include <hip/hip_bf16.h>
#include <cstdint>
#include <cstddef>

// B=4, LQ=LK=1024, D=512, H=8. fp32 in/out; bf16 MFMA compute.
// R11: 256x256 tile, BK=64 conflict-free layout, 4 phases/tile with counted
// vmcnt — but SINGLE 64KB LDS buffer staged IN PLACE (stage group issued one
// phase after its region's last read; lgkmcnt(0) before every barrier makes
// the WAR safe). 64KB -> 2 blocks/CU (launch_bounds(512,4)) restoring the
// cross-block pipe overlap that R7 had and R8-R10's 128KB killed.

typedef __bf16 bf16;
typedef __bf16 bf16x4 __attribute__((ext_vector_type(4)));
typedef __bf16 bf16x8 __attribute__((ext_vector_type(8)));
typedef float f32x4 __attribute__((ext_vector_type(4)));

__device__ inline void gload_lds16(const void* g, void* l) {
  __builtin_amdgcn_global_load_lds(
      (const __attribute__((address_space(1))) void*)g,
      (__attribute__((address_space(3))) void*)l, 16, 0, 0);
}

#define SBAR0 __builtin_amdgcn_sched_barrier(0)

// C[256,256] tile at (m0,n0) of scale*(A . B^T). 512 thr, 8 waves (2M x 4N),
// per-wave 128x64 output. LDS: ONE buffer A[256][64] + B[256][64] = 64KB.
// Swizzle: 16B chunk c of row r at slot c^(r&7) (0-conflict, R9-verified).
// Regions: S1=A rows{0-63,128-191} read P1; S2=B bands n0-1 read P1;
//          S3=B bands n2-3 read P2;   S4=A rows{64-127,192-255} read P3.
// In-place restage of tile t+1: S1',S2' in P2; S3' in P3; S4' in P4 —
// each issued after the barrier+lgkmcnt(0) that closed its region's reads.
// vmcnt: P1 end vmcnt(2) [certifies S3(t)], P2 end vmcnt(4) [S4(t)],
// P4 end vmcnt(4) [S1',S2']. Steady state 2-8 loads in flight, >=3 phases
// of prefetch slack. MODE 0: C=acc*scale (bf16). MODE 1: P=mask?exp:0 +
// atomic row sums. MODE 2: C=acc/sumrow (fp32).
template <typename CT, int MODE, int K>
__device__ __forceinline__ void gemm256(
    bf16* lds,
    const bf16* __restrict__ A, const bf16* __restrict__ B, CT* __restrict__ C,
    int lda, int ldb, int ldc, int m0, int n0, float scale,
    const unsigned* __restrict__ mrow, float* __restrict__ sumrow)
{
  const int t = threadIdx.x;            // 0..511
  const int lane = t & 63;
  const int w = t >> 6;                 // 0..7
  const int wm = w >> 2, wn = w & 3;    // 2 x 4
  const int rr = lane & 15, q4 = lane >> 4;

  // Staging thread coords (R7-proven swizzle pattern).
  const int s64row = t >> 3;                 // 0..63
  const int ssl    = t & 7;                  // dest slot
  const int s64ch  = ssl ^ (s64row & 7);     // source chunk (64-row stage)
  const int tb     = t & 255;
  const int sbrow  = tb >> 3;                // 0..31
  const int sbch   = ssl ^ (sbrow & 7);      // source chunk (32-row bands)
  const int hb     = t >> 8;                 // which band within a B stage

  constexpr int nT = K >> 6;

  // Hoisted per-thread bases.
  const bf16* Ag = A + (size_t)(m0 + s64row) * lda + s64ch * 8;
  const bf16* Bg = B + (size_t)(n0 + hb * 64 + sbrow) * ldb + sbch * 8;
  bf16* stAd = lds + t * 8;                                     // + row0*64
  bf16* stBd = lds + 16384 + (hb * 64 + sbrow) * 64 + ssl * 8;  // + b0*64

  auto stageA = [&](int tt, int row0) {
    gload_lds16(Ag + (size_t)row0 * lda + tt * 64, stAd + row0 * 64);
  };
  auto stageB = [&](int tt, int b0) {
    gload_lds16(Bg + (size_t)b0 * ldb + tt * 64, stBd + b0 * 64);
  };

  // Prologue: full tile 0 in order S1,S2,S3,S4 (8 loads); certify S1,S2.
  stageA(0, 0);   stageA(0, 128);   // S1
  stageB(0, 0);   stageB(0, 128);   // S2
  stageB(0, 32);  stageB(0, 160);   // S3
  stageA(0, 64);  stageA(0, 192);   // S4
  asm volatile("s_waitcnt vmcnt(4)" ::: "memory");
  __builtin_amdgcn_s_barrier();
  SBAR0;

  f32x4 acc[8][4] = {};
  bf16x8 af[2][4];   // [kk][m within half]
  bf16x8 bgf[2][4];  // [kk][n], registers live across the whole tile

  // Fragment swizzle collapses: R&7 == rr&7 for every fragment row.
  const int sw0 = (q4 ^ (rr & 7)) << 3;  // elem offset, kk=0
  const int sw1 = sw0 ^ 32;              // kk=1

  const bf16* Ab = lds + (wm * 128 + rr) * 64;
  const bf16* Bb = lds + 16384 + (wn * 64 + rr) * 64;

#pragma unroll
  for (int tt = 0; tt < nT; ++tt) {
    const bool pf = (tt + 1) < nT;   // compile-time after unroll

    // ---- P1: read S1(A m0-3) + S2(B n0-1); MFMA m0-3 x n0-1 ----
#pragma unroll
    for (int m = 0; m < 4; ++m) {
      af[0][m] = *(const bf16x8*)(Ab + m * 1024 + sw0);
      af[1][m] = *(const bf16x8*)(Ab + m * 1024 + sw1);
    }
#pragma unroll
    for (int n = 0; n < 2; ++n) {
      bgf[0][n] = *(const bf16x8*)(Bb + n * 1024 + sw0);
      bgf[1][n] = *(const bf16x8*)(Bb + n * 1024 + sw1);
    }
    asm volatile("s_waitcnt vmcnt(2) lgkmcnt(0)" ::: "memory");
    __builtin_amdgcn_s_barrier();
    SBAR0;
    __builtin_amdgcn_s_setprio(1);
#pragma unroll
    for (int kk = 0; kk < 2; ++kk)
#pragma unroll
      for (int m = 0; m < 4; ++m)
#pragma unroll
        for (int n = 0; n < 2; ++n)
          acc[m][n] = __builtin_amdgcn_mfma_f32_16x16x32_bf16(af[kk][m], bgf[kk][n], acc[m][n], 0, 0, 0);
    __builtin_amdgcn_s_setprio(0);

    // ---- P2: read S3(B n2-3); restage S1',S2'; MFMA m0-3 x n2-3 ----
#pragma unroll
    for (int n = 2; n < 4; ++n) {
      bgf[0][n] = *(const bf16x8*)(Bb + n * 1024 + sw0);
      bgf[1][n] = *(const bf16x8*)(Bb + n * 1024 + sw1);
    }
    if (pf) {
      stageA(tt + 1, 0); stageA(tt + 1, 128);    // S1'
      stageB(tt + 1, 0); stageB(tt + 1, 128);    // S2'
      asm volatile("s_waitcnt vmcnt(4) lgkmcnt(0)" ::: "memory");
    } else {
      asm volatile("s_waitcnt vmcnt(0) lgkmcnt(0)" ::: "memory");
    }
    __builtin_amdgcn_s_barrier();
    SBAR0;
    __builtin_amdgcn_s_setprio(1);
#pragma unroll
    for (int kk = 0; kk < 2; ++kk)
#pragma unroll
      for (int m = 0; m < 4; ++m)
#pragma unroll
        for (int n = 2; n < 4; ++n)
          acc[m][n] = __builtin_amdgcn_mfma_f32_16x16x32_bf16(af[kk][m], bgf[kk][n], acc[m][n], 0, 0, 0);
    __builtin_amdgcn_s_setprio(0);

    // ---- P3: read S4(A m4-7); restage S3'; MFMA m4-7 x n0-1 ----
#pragma unroll
    for (int m = 0; m < 4; ++m) {
      af[0][m] = *(const bf16x8*)(Ab + (64 + m * 16) * 64 + sw0);
      af[1][m] = *(const bf16x8*)(Ab + (64 + m * 16) * 64 + sw1);
    }
    if (pf) { stageB(tt + 1, 32); stageB(tt + 1, 160); }  // S3'
    asm volatile("s_waitcnt lgkmcnt(0)" ::: "memory");
    __builtin_amdgcn_s_barrier();
    SBAR0;
    __builtin_amdgcn_s_setprio(1);
#pragma unroll
    for (int kk = 0; kk < 2; ++kk)
#pragma unroll
      for (int m = 0; m < 4; ++m)
#pragma unroll
        for (int n = 0; n < 2; ++n)
          acc[4 + m][n] = __builtin_amdgcn_mfma_f32_16x16x32_bf16(af[kk][m], bgf[kk][n], acc[4 + m][n], 0, 0, 0);
    __builtin_amdgcn_s_setprio(0);

    // ---- P4: restage S4'; MFMA m4-7 x n2-3 (registers only) ----
    if (pf) {
      stageA(tt + 1, 64); stageA(tt + 1, 192);   // S4'
      asm volatile("s_waitcnt vmcnt(4)" ::: "memory");
    }
    __builtin_amdgcn_s_barrier();
    SBAR0;
    __builtin_amdgcn_s_setprio(1);
#pragma unroll
    for (int kk = 0; kk < 2; ++kk)
#pragma unroll
      for (int m = 0; m < 4; ++m)
#pragma unroll
        for (int n = 2; n < 4; ++n)
          acc[4 + m][n] = __builtin_amdgcn_mfma_f32_16x16x32_bf16(af[kk][m], bgf[kk][n], acc[4 + m][n], 0, 0, 0);
    __builtin_amdgcn_s_setprio(0);
  }

  // C/D frag: col = lane&15, row = (lane>>4)*4 + reg  (R7-R10-verified)
  if (MODE == 0) {
#pragma unroll
    for (int m = 0; m < 8; ++m) {
#pragma unroll
      for (int n = 0; n < 4; ++n) {
        const int gr0 = m0 + wm * 128 + m * 16 + (q4 << 2);
        const int gc = n0 + wn * 64 + n * 16 + rr;
#pragma unroll
        for (int i = 0; i < 4; ++i)
          C[(size_t)(gr0 + i) * ldc + gc] = (CT)(acc[m][n][i] * scale);
      }
    }
  } else if (MODE == 1) {
    const int cb0 = (n0 + wn * 64) >> 5;
#pragma unroll
    for (int m = 0; m < 8; ++m) {
#pragma unroll
      for (int i = 0; i < 4; ++i) {
        const int row = m0 + wm * 128 + m * 16 + (q4 << 2) + i;
        const unsigned mw0 = mrow[(row << 5) + cb0];
        const unsigned mw1 = mrow[(row << 5) + cb0 + 1];
        float ps = 0.0f;
#pragma unroll
        for (int n = 0; n < 4; ++n) {
          const int gc = n0 + wn * 64 + n * 16 + rr;
          const unsigned mw = (n >= 2) ? mw1 : mw0;
          const unsigned bit = (mw >> (((n & 1) << 4) + rr)) & 1u;
          float p = bit ? __expf(acc[m][n][i] * scale) : 0.0f;
          C[(size_t)row * ldc + gc] = (CT)p;
          ps += p;
        }
        ps += __shfl_xor(ps, 1); ps += __shfl_xor(ps, 2);
        ps += __shfl_xor(ps, 4); ps += __shfl_xor(ps, 8);
        if (rr == 0) atomicAdd(sumrow + row, ps);
      }
    }
  } else {
#pragma unroll
    for (int m = 0; m < 8; ++m) {
      const int gr0 = m0 + wm * 128 + m * 16 + (q4 << 2);
      float inv[4];
#pragma unroll
      for (int i = 0; i < 4; ++i) inv[i] = 1.0f / sumrow[gr0 + i];
#pragma unroll
      for (int n = 0; n < 4; ++n) {
        const int gc = n0 + wn * 64 + n * 16 + rr;
#pragma unroll
        for (int i = 0; i < 4; ++i)
          C[(size_t)(gr0 + i) * ldc + gc] = (CT)(acc[m][n][i] * inv[i]);
      }
    }
  }
}

// ---- Dispatch 1: prep (cvt5 + cvtT + pack_mask + zero sums). grid 12832. ----
__global__ __launch_bounds__(256) void prep_kernel(
    const float* __restrict__ x, const float* __restrict__ st,
    const float* __restrict__ Wq, const float* __restrict__ Wk,
    const float* __restrict__ Wp, const float* __restrict__ Wv,
    const int* __restrict__ mask,
    bf16* __restrict__ xb, bf16* __restrict__ stb, bf16* __restrict__ wqb,
    bf16* __restrict__ wkb, bf16* __restrict__ wpb, bf16* __restrict__ WvT,
    unsigned* __restrict__ mbits, float* __restrict__ sums)
{
  const int lin = blockIdx.x;
  const int t = threadIdx.x;
  if (lin < 10240) {
    const float* s; bf16* d;
    switch (lin >> 11) {
      case 0: s = x; d = xb; break;
      case 1: s = st; d = stb; break;
      case 2: s = Wq; d = wqb; break;
      case 3: s = Wk; d = wkb; break;
      default: s = Wp; d = wpb; break;
    }
    const int i = ((lin & 2047) * 256 + t) * 4;
    float4 v = *(const float4*)(s + i);
    bf16x4 o;
    o[0] = (bf16)v.x; o[1] = (bf16)v.y; o[2] = (bf16)v.z; o[3] = (bf16)v.w;
    *(bf16x4*)(d + i) = o;
  } else if (lin < 12288) {
    // WvT[h][d][e'] = Wv[h][e'][d]
    const int gid = (lin - 10240) * 256 + t;      // [0, 524288)
    const int e0 = (gid & 127) * 4;
    const int d = (gid >> 7) & 511;
    const int h = gid >> 16;
    const float* src = Wv + (size_t)h * 262144 + (size_t)e0 * 512 + d;
    bf16x4 o;
    o[0] = (bf16)src[0];
    o[1] = (bf16)src[512];
    o[2] = (bf16)src[1024];
    o[3] = (bf16)src[1536];
    *(bf16x4*)(WvT + (size_t)h * 262144 + (size_t)d * 512 + e0) = o;
  } else if (lin < 12800) {
    const int gid = (lin - 12288) * 256 + t;      // [0, 131072)
    const int* src = mask + (size_t)gid * 32;
    unsigned bits = 0;
#pragma unroll
    for (int j = 0; j < 32; j += 4) {
      int4 v = *(const int4*)(src + j);
      if (v.x) bits |= 1u << j;
      if (v.y) bits |= 1u << (j + 1);
      if (v.z) bits |= 1u << (j + 2);
      if (v.w) bits |= 1u << (j + 3);
    }
    mbits[gid] = bits;
  } else {
    const int i = ((lin - 12800) * 256 + t) * 4;  // [0, 32768) floats
    *(float4*)(sums + i) = make_float4(0.f, 0.f, 0.f, 0.f);
  }
}

// ---- Dispatch 2: proj (q/k projections + U = Wp_h.Wv_h). grid 544x512. ----
__global__ __launch_bounds__(512, 4) void proj_kernel(
    const bf16* __restrict__ xb, const bf16* __restrict__ stb,
    const bf16* __restrict__ wqb, const bf16* __restrict__ wkb,
    const bf16* __restrict__ wpb, const bf16* __restrict__ WvT,
    bf16* __restrict__ q, bf16* __restrict__ k, bf16* __restrict__ U)
{
  __shared__ bf16 lds[32768];   // 64 KB -> 2 blocks/CU
  const int bid = blockIdx.x;
  const int g = (bid & 7) * 68 + (bid >> 3);   // XCD-chunked, 544 = 8*68
  if (g < 512) {
    const int z = g >> 3;        // 0..63 : job*32 + (zb*8+zh)
    const int tile = g & 7;      // 4 m x 2 n
    const int job = z >> 5;
    const int zz = z & 31;
    const size_t zb = zz >> 3, zh = zz & 7;
    const bf16* Ain = job ? stb : xb;
    const bf16* W = job ? wkb : wqb;
    bf16* Cout = job ? k : q;
    gemm256<bf16, 0, 512>(lds, Ain + zb * 524288, W + zh * 262144,
        Cout + zb * 4194304 + zh * 524288, 512, 512, 512,
        (tile >> 1) * 256, (tile & 1) * 256, 1.0f, nullptr, nullptr);
  } else {
    // U_h[e,d] = sum_e' Wp[e, h*512+e'] * WvT_h[d, e']
    const int g2 = g - 512;      // 0..31
    const int h = g2 >> 2;
    const int tile = g2 & 3;     // 2 m x 2 n
    gemm256<bf16, 0, 512>(lds, wpb + (size_t)h * 512, WvT + (size_t)h * 262144,
        U + (size_t)h * 262144, 4096, 512, 512,
        (tile >> 1) * 256, (tile & 1) * 256, 1.0f, nullptr, nullptr);
  }
}

// ---- Dispatch 3: big (scores+exp+rowsum, and VWT = U.states^T). grid 768x512. ----
__global__ __launch_bounds__(512, 4) void big_kernel(
    const bf16* __restrict__ q, const bf16* __restrict__ k,
    const bf16* __restrict__ U, const bf16* __restrict__ stb,
    bf16* __restrict__ P, bf16* __restrict__ VWT,
    const unsigned* __restrict__ mbits, float* __restrict__ sums, float scale)
{
  __shared__ bf16 lds[32768];
  const int bid = blockIdx.x;
  const int g = (bid & 7) * 96 + (bid >> 3);   // 768 = 8*96
  if (g < 512) {
    // scores: z in [0,32), 16 tiles (4m x 4n)
    const int z = g >> 4;
    const int tile = g & 15;
    const size_t zb = z >> 3, zh = z & 7;
    gemm256<bf16, 1, 512>(lds,
        q + zb * 4194304 + zh * 524288,
        k + zb * 4194304 + zh * 524288,
        P + zb * 8388608 + zh * 1048576,
        512, 512, 1024,
        (tile >> 2) * 256, (tile & 3) * 256, scale,
        mbits + (zb << 15), sums + ((size_t)z << 10));
  } else {
    // VWT[b,h][e,s] = U_h . states_b^T : z in [0,32), 8 tiles (2m x 4n)
    const int g2 = g - 512;
    const int z = g2 >> 3;
    const int tile = g2 & 7;
    const size_t zb = z >> 3, zh = z & 7;
    gemm256<bf16, 0, 512>(lds, U + zh * 262144, stb + zb * 524288,
        VWT + zb * 4194304 + zh * 524288, 512, 512, 1024,
        (tile >> 2) * 256, (tile & 3) * 256, 1.0f, nullptr, nullptr);
  }
}

// ---- Dispatch 4: pvw — part[h] = (1/sum_h) ⊙ (P_h·VWT_h^T). grid 256x512. ----
__global__ __launch_bounds__(512, 4) void pvw_kernel(
    const bf16* __restrict__ P, const bf16* __restrict__ VWT,
    float* __restrict__ sums, float* __restrict__ part)
{
  __shared__ bf16 lds[32768];
  const int bid = blockIdx.x;
  const int g = (bid & 7) * 32 + (bid >> 3);   // 256 = 8*32
  const int z = g >> 3;        // 0..31 = (b,h)
  const int tile = g & 7;      // 4 m(l) x 2 n(e)
  const size_t zb = z >> 3, zh = z & 7;
  gemm256<float, 2, 1024>(lds,
      P + zb * 8388608 + zh * 1048576,
      VWT + zb * 4194304 + zh * 524288,
      part + zh * 2097152 + zb * 524288,
      1024, 1024, 512,
      (tile >> 1) * 256, (tile & 1) * 256, 1.0f,
      nullptr, sums + ((size_t)z << 10));
}

// ---- Dispatch 5: out = sum of 8 per-head parts. grid 2048x256. ----
__global__ __launch_bounds__(256) void reduce8(
    const float* __restrict__ part, float* __restrict__ out)
{
  const size_t i = ((size_t)blockIdx.x * 256 + threadIdx.x) * 4;
  float4 o = *(const float4*)(part + i);
#pragma unroll
  for (int h = 1; h < 8; ++h) {
    float4 a = *(const float4*)(part + (size_t)h * 2097152 + i);
    o.x += a.x; o.y += a.y; o.z += a.z; o.w += a.w;
  }
  *(float4*)(out + i) = o;
}

extern "C" void kernel_launch(void* const* d_in, const int* in_sizes, int n_in,
                              void* d_out, int out_size, void* d_ws, size_t ws_size,
                              hipStream_t stream) {
  const float* x    = (const float*)d_in[0];
  const float* st   = (const float*)d_in[1];
  const int*   mask = (const int*)d_in[2];
  const float* Wq   = (const float*)d_in[3];
  const float* Wk   = (const float*)d_in[4];
  const float* Wv   = (const float*)d_in[5];
  const float* Wp   = (const float*)d_in[6];
  float* out = (float*)d_out;

  char* ws = (char*)d_ws;
  const size_t MB = 1048576;
  bf16* xb  = (bf16*)(ws);               // 4MB
  bf16* stb = (bf16*)(ws + 4 * MB);      // 4MB (live through VWT)
  bf16* wqb = (bf16*)(ws + 8 * MB);      // 4MB
  bf16* wkb = (bf16*)(ws + 12 * MB);     // 4MB
  bf16* wpb = (bf16*)(ws + 16 * MB);     // 4MB
  bf16* WvT = (bf16*)(ws + 20 * MB);     // 4MB [8,512,512] transposed
  bf16* U   = (bf16*)(ws + 24 * MB);     // 4MB [8,512,512] Wp_h.Wv_h
  bf16* q   = (bf16*)(ws + 28 * MB);     // 32MB; dead after scores
  bf16* k   = (bf16*)(ws + 60 * MB);     // 32MB; dead after scores
  bf16* VWT = (bf16*)(ws + 92 * MB);     // 32MB [4,8,512,1024]
  bf16* sc  = (bf16*)(ws + 124 * MB);    // 64MB P = exp(scores)
  unsigned* mbits = (unsigned*)(ws + 188 * MB);  // 512KB
  float*    sums  = (float*)(ws + 189 * MB);     // 128KB
  float*    part  = (float*)(ws + 28 * MB);      // 64MB fp32 (over q+k)

  const float scale = 0.04419417382415922f;  // 1/sqrt(512)

  prep_kernel<<<dim3(12832), dim3(256), 0, stream>>>(x, st, Wq, Wk, Wp, Wv, mask,
      xb, stb, wqb, wkb, wpb, WvT, mbits, sums);

  proj_kernel<<<dim3(544), dim3(512), 0, stream>>>(xb, stb, wqb, wkb, wpb, WvT,
      q, k, U);

  big_kernel<<<dim3(768), dim3(512), 0, stream>>>(q, k, U, stb, sc, VWT,
      mbits, sums, scale);

  pvw_kernel<<<dim3(256), dim3(512), 0, stream>>>(sc, VWT, sums, part);

  reduce8<<<dim3(2048), dim3(256), 0, stream>>>(part, out);
}

// Round 6
// 303.946 us; speedup vs baseline: 4.4173x; 4.4173x over previous
//
#include <hip/hip_runtime.h>
#include <hip/hip_bf16.h>
#include <cstdint>
#include <cstddef>

// B=4, LQ=LK=1024, D=512, H=8. fp32 in/out; bf16 MFMA compute.
// R12: 128x128 tile / 256 thr / 4 waves (R7 geometry, 2 blocks/CU) with a
// counted-vmcnt DOUBLE-BUFFERED pipeline: per K-tile
//   stage(t+1) -> vmcnt(8) -> BAR1 -> 16 ds_read -> lgkm(0) -> 32 MFMA -> BAR2
// vmcnt never drains to 0 in steady state (T3/T4); setprio around MFMA (T5);
// conflict-free chunk^(row&7) LDS swizzle (T2, 0 conflicts since R9).
// BAR1 certifies cross-wave RAW (each wave's own vmcnt before it); BAR2
// certifies WAR on buffer reuse (all reads of buf t-1 done before stage t+1).

typedef __bf16 bf16;
typedef __bf16 bf16x4 __attribute__((ext_vector_type(4)));
typedef __bf16 bf16x8 __attribute__((ext_vector_type(8)));
typedef float f32x4 __attribute__((ext_vector_type(4)));

__device__ inline void gload_lds16(const void* g, void* l) {
  __builtin_amdgcn_global_load_lds(
      (const __attribute__((address_space(1))) void*)g,
      (__attribute__((address_space(3))) void*)l, 16, 0, 0);
}

#define SBAR0 __builtin_amdgcn_sched_barrier(0)

// C[128,128] tile at (m0,n0) of scale*(A . B^T). 256 thr, 4 waves (2M x 2N),
// per-wave 64x64 output (4x4 16x16 frags, 64 acc VGPR). LDS: 2 buffers x
// (A[128][64] + B[128][64]) bf16 = 64KB. Swizzle: 16B chunk c of row r at
// slot c^(r&7). MODE 0: C=acc*scale (bf16). MODE 1: P=mask?exp(acc*scale):0
// (bf16) + atomic row sums. MODE 2: C=acc/sumrow[row] (fp32).
template <typename CT, int MODE, int K>
__device__ __forceinline__ void gemm128(
    bf16* lds,
    const bf16* __restrict__ A, const bf16* __restrict__ B, CT* __restrict__ C,
    int lda, int ldb, int ldc, int m0, int n0, float scale,
    const unsigned* __restrict__ mrow, float* __restrict__ sumrow)
{
  const int t = threadIdx.x;            // 0..255
  const int lane = t & 63;
  const int w = t >> 6;                 // 0..3
  const int wm = w >> 1, wn = w & 1;    // 2 x 2
  const int rr = lane & 15, q4 = lane >> 4;

  // Staging thread coords (R7-proven swizzle pattern, 0 conflicts).
  const int srow = t >> 3;                   // 0..31
  const int ssl  = t & 7;                    // dest slot
  const int sch  = ssl ^ (srow & 7);         // source chunk (row&7-invariant
                                             // under +32*i row steps)
  constexpr int nT = K >> 6;

  const bf16* Ag = A + (size_t)(m0 + srow) * lda + sch * 8;
  const bf16* Bg = B + (size_t)(n0 + srow) * ldb + sch * 8;
  bf16* std_ = lds + t * 8;   // + (tt&1)*16384 + i*2048 (+8192 for B)

  // Stage full k-tile tt into buffer tt&1: 8 gloads (A 4 + B 4).
  auto stage = [&](int tt) {
    const bf16* As = Ag + tt * 64;
    const bf16* Bs = Bg + tt * 64;
    bf16* d = std_ + (tt & 1) * 16384;
#pragma unroll
    for (int i = 0; i < 4; ++i) {
      gload_lds16(As + (size_t)(32 * i) * lda, d + i * 2048);
      gload_lds16(Bs + (size_t)(32 * i) * ldb, d + 8192 + i * 2048);
    }
  };

  // Prologue: stage tile 0 only; certification happens at iter-0 vmcnt+BAR1.
  stage(0);

  f32x4 acc[4][4] = {};

  // Fragment swizzle collapses: R&7 == rr&7 for every fragment row.
  const int sw0 = (q4 ^ (rr & 7)) << 3;  // elem offset, kk=0
  const int sw1 = sw0 ^ 32;              // kk=1

#pragma unroll
  for (int tt = 0; tt < nT; ++tt) {
    const bool pf = (tt + 1) < nT;   // compile-time after unroll

    if (pf) stage(tt + 1);           // into buf^1; WAR-safe past BAR2(tt-1)
    if (pf) asm volatile("s_waitcnt vmcnt(8)" ::: "memory");  // own stage(tt) landed
    else    asm volatile("s_waitcnt vmcnt(0)" ::: "memory");
    __builtin_amdgcn_s_barrier();    // BAR1: ALL waves' stage(tt) landed
    SBAR0;

    const bf16* Ab = lds + (tt & 1) * 16384 + (wm * 64 + rr) * 64;
    const bf16* Bb = lds + (tt & 1) * 16384 + 8192 + (wn * 64 + rr) * 64;
    bf16x8 af[2][4], bg[2][4];
#pragma unroll
    for (int m = 0; m < 4; ++m) {
      af[0][m] = *(const bf16x8*)(Ab + m * 1024 + sw0);
      af[1][m] = *(const bf16x8*)(Ab + m * 1024 + sw1);
    }
#pragma unroll
    for (int n = 0; n < 4; ++n) {
      bg[0][n] = *(const bf16x8*)(Bb + n * 1024 + sw0);
      bg[1][n] = *(const bf16x8*)(Bb + n * 1024 + sw1);
    }
    asm volatile("s_waitcnt lgkmcnt(0)" ::: "memory");
    SBAR0;

    __builtin_amdgcn_s_setprio(1);
#pragma unroll
    for (int kk = 0; kk < 2; ++kk)
#pragma unroll
      for (int m = 0; m < 4; ++m)
#pragma unroll
        for (int n = 0; n < 4; ++n)
          acc[m][n] = __builtin_amdgcn_mfma_f32_16x16x32_bf16(af[kk][m], bg[kk][n], acc[m][n], 0, 0, 0);
    __builtin_amdgcn_s_setprio(0);

    __builtin_amdgcn_s_barrier();    // BAR2: all reads of buf tt complete
  }

  // C/D frag: col = lane&15, row = (lane>>4)*4 + reg  (R7-R11-verified)
  if (MODE == 0) {
#pragma unroll
    for (int m = 0; m < 4; ++m) {
#pragma unroll
      for (int n = 0; n < 4; ++n) {
        const int gr0 = m0 + wm * 64 + m * 16 + (q4 << 2);
        const int gc = n0 + wn * 64 + n * 16 + rr;
#pragma unroll
        for (int i = 0; i < 4; ++i)
          C[(size_t)(gr0 + i) * ldc + gc] = (CT)(acc[m][n][i] * scale);
      }
    }
  } else if (MODE == 1) {
    const int cb0 = (n0 + wn * 64) >> 5;
#pragma unroll
    for (int m = 0; m < 4; ++m) {
#pragma unroll
      for (int i = 0; i < 4; ++i) {
        const int row = m0 + wm * 64 + m * 16 + (q4 << 2) + i;
        const unsigned mw0 = mrow[(row << 5) + cb0];
        const unsigned mw1 = mrow[(row << 5) + cb0 + 1];
        float ps = 0.0f;
#pragma unroll
        for (int n = 0; n < 4; ++n) {
          const int gc = n0 + wn * 64 + n * 16 + rr;
          const unsigned mw = (n >= 2) ? mw1 : mw0;
          const unsigned bit = (mw >> (((n & 1) << 4) + rr)) & 1u;
          float p = bit ? __expf(acc[m][n][i] * scale) : 0.0f;
          C[(size_t)row * ldc + gc] = (CT)p;
          ps += p;
        }
        ps += __shfl_xor(ps, 1); ps += __shfl_xor(ps, 2);
        ps += __shfl_xor(ps, 4); ps += __shfl_xor(ps, 8);
        if (rr == 0) atomicAdd(sumrow + row, ps);
      }
    }
  } else {
#pragma unroll
    for (int m = 0; m < 4; ++m) {
      const int gr0 = m0 + wm * 64 + m * 16 + (q4 << 2);
      float inv[4];
#pragma unroll
      for (int i = 0; i < 4; ++i) inv[i] = 1.0f / sumrow[gr0 + i];
#pragma unroll
      for (int n = 0; n < 4; ++n) {
        const int gc = n0 + wn * 64 + n * 16 + rr;
#pragma unroll
        for (int i = 0; i < 4; ++i)
          C[(size_t)(gr0 + i) * ldc + gc] = (CT)(acc[m][n][i] * inv[i]);
      }
    }
  }
}

// ---- Dispatch 1: prep (cvt5 + cvtT + pack_mask + zero sums). grid 12832. ----
__global__ __launch_bounds__(256) void prep_kernel(
    const float* __restrict__ x, const float* __restrict__ st,
    const float* __restrict__ Wq, const float* __restrict__ Wk,
    const float* __restrict__ Wp, const float* __restrict__ Wv,
    const int* __restrict__ mask,
    bf16* __restrict__ xb, bf16* __restrict__ stb, bf16* __restrict__ wqb,
    bf16* __restrict__ wkb, bf16* __restrict__ wpb, bf16* __restrict__ WvT,
    unsigned* __restrict__ mbits, float* __restrict__ sums)
{
  const int lin = blockIdx.x;
  const int t = threadIdx.x;
  if (lin < 10240) {
    const float* s; bf16* d;
    switch (lin >> 11) {
      case 0: s = x; d = xb; break;
      case 1: s = st; d = stb; break;
      case 2: s = Wq; d = wqb; break;
      case 3: s = Wk; d = wkb; break;
      default: s = Wp; d = wpb; break;
    }
    const int i = ((lin & 2047) * 256 + t) * 4;
    float4 v = *(const float4*)(s + i);
    bf16x4 o;
    o[0] = (bf16)v.x; o[1] = (bf16)v.y; o[2] = (bf16)v.z; o[3] = (bf16)v.w;
    *(bf16x4*)(d + i) = o;
  } else if (lin < 12288) {
    // WvT[h][d][e'] = Wv[h][e'][d]
    const int gid = (lin - 10240) * 256 + t;      // [0, 524288)
    const int e0 = (gid & 127) * 4;
    const int d = (gid >> 7) & 511;
    const int h = gid >> 16;
    const float* src = Wv + (size_t)h * 262144 + (size_t)e0 * 512 + d;
    bf16x4 o;
    o[0] = (bf16)src[0];
    o[1] = (bf16)src[512];
    o[2] = (bf16)src[1024];
    o[3] = (bf16)src[1536];
    *(bf16x4*)(WvT + (size_t)h * 262144 + (size_t)d * 512 + e0) = o;
  } else if (lin < 12800) {
    const int gid = (lin - 12288) * 256 + t;      // [0, 131072)
    const int* src = mask + (size_t)gid * 32;
    unsigned bits = 0;
#pragma unroll
    for (int j = 0; j < 32; j += 4) {
      int4 v = *(const int4*)(src + j);
      if (v.x) bits |= 1u << j;
      if (v.y) bits |= 1u << (j + 1);
      if (v.z) bits |= 1u << (j + 2);
      if (v.w) bits |= 1u << (j + 3);
    }
    mbits[gid] = bits;
  } else {
    const int i = ((lin - 12800) * 256 + t) * 4;  // [0, 32768) floats
    *(float4*)(sums + i) = make_float4(0.f, 0.f, 0.f, 0.f);
  }
}

// ---- Dispatch 2: proj (q/k projections + U = Wp_h.Wv_h). grid 2176x256. ----
__global__ __launch_bounds__(256, 2) void proj_kernel(
    const bf16* __restrict__ xb, const bf16* __restrict__ stb,
    const bf16* __restrict__ wqb, const bf16* __restrict__ wkb,
    const bf16* __restrict__ wpb, const bf16* __restrict__ WvT,
    bf16* __restrict__ q, bf16* __restrict__ k, bf16* __restrict__ U)
{
  __shared__ bf16 lds[32768];   // 64 KB -> 2 blocks/CU
  const int bid = blockIdx.x;
  const int g = (bid & 7) * 272 + (bid >> 3);   // XCD-chunked, 2176 = 8*272
  if (g < 2048) {
    const int z = g >> 5;        // 0..63 : job*32 + (zb*8+zh)
    const int tile = g & 31;     // 8 m x 4 n
    const int job = z >> 5;
    const int zz = z & 31;
    const size_t zb = zz >> 3, zh = zz & 7;
    const bf16* Ain = job ? stb : xb;
    const bf16* W = job ? wkb : wqb;
    bf16* Cout = job ? k : q;
    gemm128<bf16, 0, 512>(lds, Ain + zb * 524288, W + zh * 262144,
        Cout + zb * 4194304 + zh * 524288, 512, 512, 512,
        (tile >> 2) * 128, (tile & 3) * 128, 1.0f, nullptr, nullptr);
  } else {
    // U_h[e,d] = sum_e' Wp[e, h*512+e'] * WvT_h[d, e']
    const int g2 = g - 2048;     // 0..127
    const int h = g2 >> 4;
    const int tile = g2 & 15;    // 4 m x 4 n
    gemm128<bf16, 0, 512>(lds, wpb + (size_t)h * 512, WvT + (size_t)h * 262144,
        U + (size_t)h * 262144, 4096, 512, 512,
        (tile >> 2) * 128, (tile & 3) * 128, 1.0f, nullptr, nullptr);
  }
}

// ---- Dispatch 3: big (scores+exp+rowsum, and VWT = U.states^T). grid 3072x256. ----
__global__ __launch_bounds__(256, 2) void big_kernel(
    const bf16* __restrict__ q, const bf16* __restrict__ k,
    const bf16* __restrict__ U, const bf16* __restrict__ stb,
    bf16* __restrict__ P, bf16* __restrict__ VWT,
    const unsigned* __restrict__ mbits, float* __restrict__ sums, float scale)
{
  __shared__ bf16 lds[32768];
  const int bid = blockIdx.x;
  const int g = (bid & 7) * 384 + (bid >> 3);   // 3072 = 8*384
  if (g < 2048) {
    // scores: z in [0,32), 64 tiles (8m x 8n)
    const int z = g >> 6;
    const int tile = g & 63;
    const size_t zb = z >> 3, zh = z & 7;
    gemm128<bf16, 1, 512>(lds,
        q + zb * 4194304 + zh * 524288,
        k + zb * 4194304 + zh * 524288,
        P + zb * 8388608 + zh * 1048576,
        512, 512, 1024,
        (tile >> 3) * 128, (tile & 7) * 128, scale,
        mbits + (zb << 15), sums + ((size_t)z << 10));
  } else {
    // VWT[b,h][e,s] = U_h . states_b^T : z in [0,32), 32 tiles (4m x 8n)
    const int g2 = g - 2048;
    const int z = g2 >> 5;
    const int tile = g2 & 31;
    const size_t zb = z >> 3, zh = z & 7;
    gemm128<bf16, 0, 512>(lds, U + zh * 262144, stb + zb * 524288,
        VWT + zb * 4194304 + zh * 524288, 512, 512, 1024,
        (tile >> 3) * 128, (tile & 7) * 128, 1.0f, nullptr, nullptr);
  }
}

// ---- Dispatch 4: pvw — part[h] = (1/sum_h) ⊙ (P_h·VWT_h^T). grid 1024x256. ----
__global__ __launch_bounds__(256, 2) void pvw_kernel(
    const bf16* __restrict__ P, const bf16* __restrict__ VWT,
    float* __restrict__ sums, float* __restrict__ part)
{
  __shared__ bf16 lds[32768];
  const int bid = blockIdx.x;
  const int g = (bid & 7) * 128 + (bid >> 3);   // 1024 = 8*128
  const int z = g >> 5;        // 0..31 = (b,h)
  const int tile = g & 31;     // 8 m(l) x 4 n(e)
  const size_t zb = z >> 3, zh = z & 7;
  gemm128<float, 2, 1024>(lds,
      P + zb * 8388608 + zh * 1048576,
      VWT + zb * 4194304 + zh * 524288,
      part + zh * 2097152 + zb * 524288,
      1024, 1024, 512,
      (tile >> 2) * 128, (tile & 3) * 128, 1.0f,
      nullptr, sums + ((size_t)z << 10));
}

// ---- Dispatch 5: out = sum of 8 per-head parts. grid 2048x256. ----
__global__ __launch_bounds__(256) void reduce8(
    const float* __restrict__ part, float* __restrict__ out)
{
  const size_t i = ((size_t)blockIdx.x * 256 + threadIdx.x) * 4;
  float4 o = *(const float4*)(part + i);
#pragma unroll
  for (int h = 1; h < 8; ++h) {
    float4 a = *(const float4*)(part + (size_t)h * 2097152 + i);
    o.x += a.x; o.y += a.y; o.z += a.z; o.w += a.w;
  }
  *(float4*)(out + i) = o;
}

extern "C" void kernel_launch(void* const* d_in, const int* in_sizes, int n_in,
                              void* d_out, int out_size, void* d_ws, size_t ws_size,
                              hipStream_t stream) {
  const float* x    = (const float*)d_in[0];
  const float* st   = (const float*)d_in[1];
  const int*   mask = (const int*)d_in[2];
  const float* Wq   = (const float*)d_in[3];
  const float* Wk   = (const float*)d_in[4];
  const float* Wv   = (const float*)d_in[5];
  const float* Wp   = (const float*)d_in[6];
  float* out = (float*)d_out;

  char* ws = (char*)d_ws;
  const size_t MB = 1048576;
  bf16* xb  = (bf16*)(ws);               // 4MB
  bf16* stb = (bf16*)(ws + 4 * MB);      // 4MB (live through VWT)
  bf16* wqb = (bf16*)(ws + 8 * MB);      // 4MB
  bf16* wkb = (bf16*)(ws + 12 * MB);     // 4MB
  bf16* wpb = (bf16*)(ws + 16 * MB);     // 4MB
  bf16* WvT = (bf16*)(ws + 20 * MB);     // 4MB [8,512,512] transposed
  bf16* U   = (bf16*)(ws + 24 * MB);     // 4MB [8,512,512] Wp_h.Wv_h
  bf16* q   = (bf16*)(ws + 28 * MB);     // 32MB; dead after scores
  bf16* k   = (bf16*)(ws + 60 * MB);     // 32MB; dead after scores
  bf16* VWT = (bf16*)(ws + 92 * MB);     // 32MB [4,8,512,1024]
  bf16* sc  = (bf16*)(ws + 124 * MB);    // 64MB P = exp(scores)
  unsigned* mbits = (unsigned*)(ws + 188 * MB);  // 512KB
  float*    sums  = (float*)(ws + 189 * MB);     // 128KB
  float*    part  = (float*)(ws + 28 * MB);      // 64MB fp32 (over q+k)

  const float scale = 0.04419417382415922f;  // 1/sqrt(512)

  prep_kernel<<<dim3(12832), dim3(256), 0, stream>>>(x, st, Wq, Wk, Wp, Wv, mask,
      xb, stb, wqb, wkb, wpb, WvT, mbits, sums);

  proj_kernel<<<dim3(2176), dim3(256), 0, stream>>>(xb, stb, wqb, wkb, wpb, WvT,
      q, k, U);

  big_kernel<<<dim3(3072), dim3(256), 0, stream>>>(q, k, U, stb, sc, VWT,
      mbits, sums, scale);

  pvw_kernel<<<dim3(1024), dim3(256), 0, stream>>>(sc, VWT, sums, part);

  reduce8<<<dim3(2048), dim3(256), 0, stream>>>(part, out);
}

// Round 7
// 284.359 us; speedup vs baseline: 4.7216x; 1.0689x over previous
//
#include <hip/hip_runtime.h>
#include <hip/hip_bf16.h>
#include <cstdint>
#include <cstddef>

// B=4, LQ=LK=1024, D=512, H=8. fp32 in/out; bf16 MFMA compute.
// R13: algebraic restructure on the PROVEN R7 engine (2-barrier 128x128 tile,
// 32KB LDS, ~3 blocks/CU TLP — best measured big_kernel at 79us; every
// R8-R12 schedule variant measured worse).
//   Mt_h = Wk_h^T.Wq_h  =>  scores = (x.Mt^T).states^T
// kills one projection GEMM per (b,h) (q AND k replaced by single t) and the
// 64MB q/k round trip. U = Wp_h.Wv_h trick unchanged.
// Dispatches: prep -> combine(Mt,U) -> stage2(t,VWT) -> big(scores) -> pvw -> reduce4.

typedef __bf16 bf16;
typedef __bf16 bf16x4 __attribute__((ext_vector_type(4)));
typedef __bf16 bf16x8 __attribute__((ext_vector_type(8)));
typedef float f32x4 __attribute__((ext_vector_type(4)));

__device__ inline void gload_lds16(const void* g, void* l) {
  __builtin_amdgcn_global_load_lds(
      (const __attribute__((address_space(1))) void*)g,
      (__attribute__((address_space(3))) void*)l, 16, 0, 0);
}

// Tile body: C[128,128] at (m0,n0) of scale*(A . B^T). BK=64, 256 thr.
// LDS swizzle: global 16B-chunk c of row r lives at slot c ^ (r&7).
// MODE 0: C = acc*scale (CT).
// MODE 1: P = maskbit ? exp(acc*scale) : 0 -> C (bf16); atomicAdd row sums.
// (verbatim R7 body — measured 79us on the 51.6GF big dispatch, 0 conflicts)
template <typename CT, int MODE>
__device__ __forceinline__ void gemm_body(
    bf16* As, bf16* Bs,
    const bf16* __restrict__ A, const bf16* __restrict__ B, CT* __restrict__ C,
    int K, int lda, int ldb, int ldc, int m0, int n0, float scale,
    const unsigned* __restrict__ mrow, float* __restrict__ sumrow)
{
  const int t = threadIdx.x;
  const int lane = t & 63, w = t >> 6;
  const int wm = w >> 1, wn = w & 1;

  const int srow = t >> 3;                       // 0..31
  const int schunk = (t & 7) ^ (srow & 7);       // swizzled source chunk
  const bf16* Ag = A + (size_t)(m0 + srow) * lda + schunk * 8;
  const bf16* Bg = B + (size_t)(n0 + srow) * ldb + schunk * 8;
  bf16* Als = As + t * 8;
  bf16* Bls = Bs + t * 8;

  f32x4 acc[4][4] = {};
  const int rr = lane & 15;
  const int q4 = lane >> 4;

  const int kIters = K >> 6;
  for (int kt = 0; kt < kIters; ++kt) {
    __syncthreads();
#pragma unroll
    for (int i = 0; i < 4; ++i) {
      gload_lds16(Ag + (size_t)(32 * i) * lda, Als + i * 2048);
      gload_lds16(Bg + (size_t)(32 * i) * ldb, Bls + i * 2048);
    }
    Ag += 64; Bg += 64;
    __syncthreads();

#pragma unroll
    for (int kk = 0; kk < 2; ++kk) {
      bf16x8 af[4], bfr[4];
      const int ck = kk * 4 + q4;
#pragma unroll
      for (int r = 0; r < 4; ++r) {
        const int R = wm * 64 + r * 16 + rr;
        af[r] = *(const bf16x8*)(As + R * 64 + ((ck ^ (R & 7)) << 3));
      }
#pragma unroll
      for (int c = 0; c < 4; ++c) {
        const int R = wn * 64 + c * 16 + rr;
        bfr[c] = *(const bf16x8*)(Bs + R * 64 + ((ck ^ (R & 7)) << 3));
      }
#pragma unroll
      for (int r = 0; r < 4; ++r)
#pragma unroll
        for (int c = 0; c < 4; ++c)
          acc[r][c] = __builtin_amdgcn_mfma_f32_16x16x32_bf16(af[r], bfr[c], acc[r][c], 0, 0, 0);
    }
  }

  // C/D frag: col = lane&15, row = (lane>>4)*4 + reg
  if (MODE == 0) {
#pragma unroll
    for (int r = 0; r < 4; ++r) {
#pragma unroll
      for (int c = 0; c < 4; ++c) {
        const int gr0 = m0 + wm * 64 + r * 16 + (q4 << 2);
        const int gc = n0 + wn * 64 + c * 16 + rr;
#pragma unroll
        for (int i = 0; i < 4; ++i)
          C[(size_t)(gr0 + i) * ldc + gc] = (CT)(acc[r][c][i] * scale);
      }
    }
  } else {
    const int cb0 = (n0 + wn * 64) >> 5;
#pragma unroll
    for (int r = 0; r < 4; ++r) {
#pragma unroll
      for (int i = 0; i < 4; ++i) {
        const int row = m0 + wm * 64 + r * 16 + (q4 << 2) + i;
        const unsigned mw0 = mrow[(row << 5) + cb0];
        const unsigned mw1 = mrow[(row << 5) + cb0 + 1];
        float ps = 0.0f;
#pragma unroll
        for (int c = 0; c < 4; ++c) {
          const int gc = n0 + wn * 64 + c * 16 + rr;
          const unsigned mw = (c >= 2) ? mw1 : mw0;
          const unsigned bit = (mw >> (((c & 1) << 4) + rr)) & 1u;
          float p = bit ? __expf(acc[r][c][i] * scale) : 0.0f;
          C[(size_t)row * ldc + gc] = (CT)p;
          ps += p;
        }
        ps += __shfl_xor(ps, 1); ps += __shfl_xor(ps, 2);
        ps += __shfl_xor(ps, 4); ps += __shfl_xor(ps, 8);
        if (rr == 0) atomicAdd(sumrow + row, ps);
      }
    }
  }
}

// ---- Dispatch 1: prep (cvt x,st,Wp + transpose Wq,Wk,Wv + mask + zero).
// grid 12832x256. ----
__global__ __launch_bounds__(256) void prep_kernel(
    const float* __restrict__ x, const float* __restrict__ st,
    const float* __restrict__ Wp, const float* __restrict__ Wq,
    const float* __restrict__ Wk, const float* __restrict__ Wv,
    const int* __restrict__ mask,
    bf16* __restrict__ xb, bf16* __restrict__ stb, bf16* __restrict__ wpb,
    bf16* __restrict__ WqT, bf16* __restrict__ WkT, bf16* __restrict__ WvT,
    unsigned* __restrict__ mbits, float* __restrict__ sums)
{
  const int lin = blockIdx.x;
  const int t = threadIdx.x;
  if (lin < 6144) {
    const float* s; bf16* d;
    switch (lin >> 11) {
      case 0: s = x; d = xb; break;
      case 1: s = st; d = stb; break;
      default: s = Wp; d = wpb; break;
    }
    const int i = ((lin & 2047) * 256 + t) * 4;
    float4 v = *(const float4*)(s + i);
    bf16x4 o;
    o[0] = (bf16)v.x; o[1] = (bf16)v.y; o[2] = (bf16)v.z; o[3] = (bf16)v.w;
    *(bf16x4*)(d + i) = o;
  } else if (lin < 12288) {
    // WT[h][d][e] = W[h][e][d]
    const int tid = lin - 6144;
    const float* s; bf16* d;
    switch (tid >> 11) {
      case 0: s = Wq; d = WqT; break;
      case 1: s = Wk; d = WkT; break;
      default: s = Wv; d = WvT; break;
    }
    const int gid = (tid & 2047) * 256 + t;       // [0, 524288)
    const int e0 = (gid & 127) * 4;
    const int dd = (gid >> 7) & 511;
    const int h = gid >> 16;
    const float* src = s + (size_t)h * 262144 + (size_t)e0 * 512 + dd;
    bf16x4 o;
    o[0] = (bf16)src[0];
    o[1] = (bf16)src[512];
    o[2] = (bf16)src[1024];
    o[3] = (bf16)src[1536];
    *(bf16x4*)(d + (size_t)h * 262144 + (size_t)dd * 512 + e0) = o;
  } else if (lin < 12800) {
    const int gid = (lin - 12288) * 256 + t;      // [0, 131072)
    const int* src = mask + (size_t)gid * 32;
    unsigned bits = 0;
#pragma unroll
    for (int j = 0; j < 32; j += 4) {
      int4 v = *(const int4*)(src + j);
      if (v.x) bits |= 1u << j;
      if (v.y) bits |= 1u << (j + 1);
      if (v.z) bits |= 1u << (j + 2);
      if (v.w) bits |= 1u << (j + 3);
    }
    mbits[gid] = bits;
  } else {
    const int i = ((lin - 12800) * 256 + t) * 4;  // [0, 32768) floats
    *(float4*)(sums + i) = make_float4(0.f, 0.f, 0.f, 0.f);
  }
}

// ---- Dispatch 2: combine — Mt_h = WkT_h.WqT_h^T, U_h = Wp_h.WvT_h^T.
// grid 256x256 (8 XCD x 32). ----
__global__ __launch_bounds__(256) void combine_kernel(
    const bf16* __restrict__ WqT, const bf16* __restrict__ WkT,
    const bf16* __restrict__ wpb, const bf16* __restrict__ WvT,
    bf16* __restrict__ Mt, bf16* __restrict__ U)
{
  __shared__ bf16 As[128 * 64];
  __shared__ bf16 Bs[128 * 64];
  const int bid = blockIdx.x;
  const int g = (bid & 7) * 32 + (bid >> 3);     // [0,256)
  const int h = (g >> 4) & 7;
  const int tile = g & 15;                       // 4m x 4n
  if (g < 128) {
    // Mt_h[d',d] = sum_e WkT[d',e] * WqT[d,e]
    gemm_body<bf16, 0>(As, Bs, WkT + (size_t)h * 262144, WqT + (size_t)h * 262144,
        Mt + (size_t)h * 262144, 512, 512, 512, 512,
        (tile >> 2) * 128, (tile & 3) * 128, 1.0f, nullptr, nullptr);
  } else {
    // U_h[e,d] = sum_e' Wp[e, h*512+e'] * WvT_h[d, e']
    gemm_body<bf16, 0>(As, Bs, wpb + (size_t)h * 512, WvT + (size_t)h * 262144,
        U + (size_t)h * 262144, 512, 4096, 512, 512,
        (tile >> 2) * 128, (tile & 3) * 128, 1.0f, nullptr, nullptr);
  }
}

// ---- Dispatch 3: stage2 — t_bh = x_b.Mt_h^T, VWT = U_h.states_b^T.
// grid 2048x256 (8 XCD x 256). ----
__global__ __launch_bounds__(256) void stage2_kernel(
    const bf16* __restrict__ xb, const bf16* __restrict__ stb,
    const bf16* __restrict__ Mt, const bf16* __restrict__ U,
    bf16* __restrict__ tq, bf16* __restrict__ VWT)
{
  __shared__ bf16 As[128 * 64];
  __shared__ bf16 Bs[128 * 64];
  const int bid = blockIdx.x;
  const int g = (bid & 7) * 256 + (bid >> 3);    // [0,2048)
  if (g < 1024) {
    // t[z][l,d'] = sum_d x_b[l,d] Mt_h[d',d]; z = zb*8+zh
    const int z = g >> 5;
    const int tile = g & 31;                     // 8m x 4n
    const size_t zb = z >> 3, zh = z & 7;
    gemm_body<bf16, 0>(As, Bs, xb + zb * 524288, Mt + zh * 262144,
        tq + (size_t)z * 524288, 512, 512, 512, 512,
        (tile >> 2) * 128, (tile & 3) * 128, 1.0f, nullptr, nullptr);
  } else {
    // VWT[b,h][e,s] = U_h . states_b^T
    const int g2 = g - 1024;
    const int z = g2 >> 5;
    const int j = g2 & 31;                       // 4m x 8n
    const size_t zb = z >> 3, zh = z & 7;
    gemm_body<bf16, 0>(As, Bs, U + zh * 262144, stb + zb * 524288,
        VWT + zb * 4194304 + zh * 524288, 512, 512, 512, 1024,
        (j >> 3) * 128, (j & 7) * 128, 1.0f, nullptr, nullptr);
  }
}

// ---- Dispatch 4: big — P = mask ? exp(scale * t.states^T) : 0, + row sums.
// grid 2048x256 (8 XCD x 256). ----
__global__ __launch_bounds__(256) void big_kernel(
    const bf16* __restrict__ tq, const bf16* __restrict__ stb,
    bf16* __restrict__ P,
    const unsigned* __restrict__ mbits, float* __restrict__ sums, float scale)
{
  __shared__ bf16 As[128 * 64];
  __shared__ bf16 Bs[128 * 64];
  const int bid = blockIdx.x;
  const int g = (bid & 7) * 256 + (bid >> 3);    // [0,2048)
  const int z = g >> 6;                          // [0,32)
  const int j = g & 63;                          // 8m x 8n
  const size_t zb = z >> 3, zh = z & 7;
  gemm_body<bf16, 1>(As, Bs,
      tq + (size_t)z * 524288,
      stb + zb * 524288,
      P + zb * 8388608 + zh * 1048576,
      512, 512, 512, 1024,
      (j >> 3) * 128, (j & 7) * 128, scale,
      mbits + (zb << 15), sums + ((size_t)z << 10));
}

// ---- Dispatch 5: pvw — out_part[hp] = sum_{h in pair} sinv_h ⊙ (P_h·VWT_h^T).
// grid 512x256 (verbatim R7). fp32 out. ----
__global__ __launch_bounds__(256) void pvw_kernel(
    const bf16* __restrict__ P, const bf16* __restrict__ VWT,
    const float* __restrict__ sums, float* __restrict__ part)
{
  __shared__ bf16 As[128 * 64];
  __shared__ bf16 Bs[128 * 64];
  const int lin = blockIdx.x;
  const int z = ((lin >> 8) << 3) | (lin & 7);    // [0,16)
  const int j = (lin >> 3) & 31;
  const int zb = z >> 2, hp = z & 3;
  const int m0 = (j >> 2) * 128, n0 = (j & 3) * 128;
  const int t = threadIdx.x;
  const int lane = t & 63, w = t >> 6;
  const int wm = w >> 1, wn = w & 1;
  const int srow = t >> 3, schunk = (t & 7) ^ (srow & 7);
  const int rr = lane & 15, q4 = lane >> 4;
  bf16* Als = As + t * 8;
  bf16* Bls = Bs + t * 8;

  f32x4 accO[4][4] = {};

#pragma unroll
  for (int hh = 0; hh < 2; ++hh) {
    const int h = hp * 2 + hh;
    const bf16* Ag = P + (size_t)zb * 8388608 + (size_t)h * 1048576
                       + (size_t)(m0 + srow) * 1024 + schunk * 8;
    const bf16* Bg = VWT + (size_t)zb * 4194304 + (size_t)h * 524288
                        + (size_t)(n0 + srow) * 1024 + schunk * 8;
    f32x4 acc[4][4] = {};
    for (int kt = 0; kt < 16; ++kt) {
      __syncthreads();
#pragma unroll
      for (int i = 0; i < 4; ++i) {
        gload_lds16(Ag + (size_t)(32 * i) * 1024, Als + i * 2048);
        gload_lds16(Bg + (size_t)(32 * i) * 1024, Bls + i * 2048);
      }
      Ag += 64; Bg += 64;
      __syncthreads();
#pragma unroll
      for (int kk = 0; kk < 2; ++kk) {
        bf16x8 af[4], bfr[4];
        const int ck = kk * 4 + q4;
#pragma unroll
        for (int r = 0; r < 4; ++r) {
          const int R = wm * 64 + r * 16 + rr;
          af[r] = *(const bf16x8*)(As + R * 64 + ((ck ^ (R & 7)) << 3));
        }
#pragma unroll
        for (int c = 0; c < 4; ++c) {
          const int R = wn * 64 + c * 16 + rr;
          bfr[c] = *(const bf16x8*)(Bs + R * 64 + ((ck ^ (R & 7)) << 3));
        }
#pragma unroll
        for (int r = 0; r < 4; ++r)
#pragma unroll
          for (int c = 0; c < 4; ++c)
            acc[r][c] = __builtin_amdgcn_mfma_f32_16x16x32_bf16(af[r], bfr[c], acc[r][c], 0, 0, 0);
      }
    }
    const float* srs = sums + ((size_t)zb * 8 + h) * 1024;
#pragma unroll
    for (int r = 0; r < 4; ++r) {
#pragma unroll
      for (int i = 0; i < 4; ++i) {
        const float inv = 1.0f / srs[m0 + wm * 64 + r * 16 + (q4 << 2) + i];
#pragma unroll
        for (int c = 0; c < 4; ++c)
          accO[r][c][i] += acc[r][c][i] * inv;
      }
    }
  }

  float* Cp = part + (size_t)hp * 2097152 + (size_t)zb * 524288;
#pragma unroll
  for (int r = 0; r < 4; ++r) {
#pragma unroll
    for (int c = 0; c < 4; ++c) {
      const int gr0 = m0 + wm * 64 + r * 16 + (q4 << 2);
      const int gc = n0 + wn * 64 + c * 16 + rr;
#pragma unroll
      for (int i = 0; i < 4; ++i)
        Cp[(size_t)(gr0 + i) * 512 + gc] = accO[r][c][i];
    }
  }
}

// ---- Dispatch 6: out = part0+part1+part2+part3. grid 2048x256. ----
__global__ __launch_bounds__(256) void reduce4(
    const float* __restrict__ part, float* __restrict__ out)
{
  const size_t i = ((size_t)blockIdx.x * 256 + threadIdx.x) * 4;
  float4 a = *(const float4*)(part + i);
  float4 b = *(const float4*)(part + 2097152 + i);
  float4 c = *(const float4*)(part + 4194304 + i);
  float4 d = *(const float4*)(part + 6291456 + i);
  float4 o;
  o.x = (a.x + b.x) + (c.x + d.x);
  o.y = (a.y + b.y) + (c.y + d.y);
  o.z = (a.z + b.z) + (c.z + d.z);
  o.w = (a.w + b.w) + (c.w + d.w);
  *(float4*)(out + i) = o;
}

extern "C" void kernel_launch(void* const* d_in, const int* in_sizes, int n_in,
                              void* d_out, int out_size, void* d_ws, size_t ws_size,
                              hipStream_t stream) {
  const float* x    = (const float*)d_in[0];
  const float* st   = (const float*)d_in[1];
  const int*   mask = (const int*)d_in[2];
  const float* Wq   = (const float*)d_in[3];
  const float* Wk   = (const float*)d_in[4];
  const float* Wv   = (const float*)d_in[5];
  const float* Wp   = (const float*)d_in[6];
  float* out = (float*)d_out;

  char* ws = (char*)d_ws;
  const size_t MB = 1048576;
  bf16* xb  = (bf16*)(ws);               // 4MB
  bf16* stb = (bf16*)(ws + 4 * MB);      // 4MB (live through big)
  bf16* wpb = (bf16*)(ws + 8 * MB);      // 4MB
  bf16* WqT = (bf16*)(ws + 12 * MB);     // 4MB [8,512,512] Wq transposed
  bf16* WkT = (bf16*)(ws + 16 * MB);     // 4MB
  bf16* WvT = (bf16*)(ws + 20 * MB);     // 4MB
  bf16* U   = (bf16*)(ws + 24 * MB);     // 4MB [8,512,512] Wp_h.Wv_h
  bf16* Mt  = (bf16*)(ws + 28 * MB);     // 4MB [8,512,512] Wk_h^T.Wq_h
  bf16* tq  = (bf16*)(ws + 32 * MB);     // 32MB [4,8,1024,512]; dead after big
  bf16* VWT = (bf16*)(ws + 64 * MB);     // 32MB [4,8,512,1024]
  bf16* sc  = (bf16*)(ws + 96 * MB);     // 64MB P = exp(scores)
  unsigned* mbits = (unsigned*)(ws + 160 * MB);  // 512KB
  float*    sums  = (float*)(ws + 161 * MB);     // 128KB
  float*    part  = (float*)(ws + 32 * MB);      // 32MB fp32 (over tq)

  dim3 blk(256);
  const float scale = 0.04419417382415922f;  // 1/sqrt(512)

  prep_kernel<<<dim3(12832), blk, 0, stream>>>(x, st, Wp, Wq, Wk, Wv, mask,
      xb, stb, wpb, WqT, WkT, WvT, mbits, sums);

  combine_kernel<<<dim3(256), blk, 0, stream>>>(WqT, WkT, wpb, WvT, Mt, U);

  stage2_kernel<<<dim3(2048), blk, 0, stream>>>(xb, stb, Mt, U, tq, VWT);

  big_kernel<<<dim3(2048), blk, 0, stream>>>(tq, stb, sc, mbits, sums, scale);

  pvw_kernel<<<dim3(512), blk, 0, stream>>>(sc, VWT, sums, part);

  reduce4<<<dim3(2048), blk, 0, stream>>>(part, out);
}